// Round 1
// baseline (545.333 us; speedup 1.0000x reference)
//
#include <hip/hip_runtime.h>
#include <stdint.h>

#define SEQ   2048
#define HID   4096
#define NQH   32
#define NKVH  8
#define HD    128
#define QKVN  6144   // (32 + 2*8) * 128

typedef uint16_t u16;
typedef __attribute__((ext_vector_type(8))) short bf16x8;
typedef __attribute__((ext_vector_type(4))) float f32x4;
typedef __attribute__((ext_vector_type(4))) unsigned int u32x4;

static __device__ __forceinline__ float bf2f(u16 h){
  union { float f; unsigned int u; } v; v.u = ((unsigned int)h) << 16; return v.f;
}
static __device__ __forceinline__ u16 f2bf(float f){
  unsigned int u = __float_as_uint(f);
  return (u16)((u + 0x7fffu + ((u >> 16) & 1u)) >> 16);  // RNE, finite inputs only
}
static __device__ __forceinline__ f32x4 mfma16(bf16x8 a, bf16x8 b, f32x4 c){
  return __builtin_amdgcn_mfma_f32_16x16x32_bf16(a, b, c, 0, 0, 0);
}

// ---------------- fp32 -> bf16 elementwise (n4 = n/4) ----------------
__global__ void k_cvt(const float* __restrict__ src, u16* __restrict__ dst, int n4){
  int i = blockIdx.x * blockDim.x + threadIdx.x;
  if (i >= n4) return;
  float4 v = ((const float4*)src)[i];
  uint2 o;
  o.x = (unsigned)f2bf(v.x) | ((unsigned)f2bf(v.y) << 16);
  o.y = (unsigned)f2bf(v.z) | ((unsigned)f2bf(v.w) << 16);
  ((uint2*)dst)[i] = o;
}

// ---------------- src[K][N] fp32 -> dst[N][K] bf16 (transpose-convert) ----------------
__global__ void k_transpose_cvt(const float* __restrict__ src, u16* __restrict__ dst, int K, int N){
  __shared__ float t[32][33];
  int n0 = blockIdx.x * 32, k0 = blockIdx.y * 32;
  int tx = threadIdx.x, ty = threadIdx.y;
#pragma unroll
  for (int i = 0; i < 32; i += 8)
    t[ty + i][tx] = src[(size_t)(k0 + ty + i) * N + n0 + tx];
  __syncthreads();
#pragma unroll
  for (int i = 0; i < 32; i += 8)
    dst[(size_t)(n0 + ty + i) * K + k0 + tx] = f2bf(t[tx][ty + i]);
}

// ---------------- C[M][N] = A[M][K] @ Bt[N][K]^T, bf16 in, OUTBF? bf16 : fp32 out ----------------
// 128x128 tile, BK=32, 4 waves (2x2), each wave 4x4 frags of 16x16x32 MFMA.
template<int OUTBF>
__global__ __launch_bounds__(256) void k_gemm(const u16* __restrict__ A, const u16* __restrict__ Bt,
                                              void* __restrict__ Cv, int M, int N, int K){
  __shared__ __align__(16) u16 Asm[128][40];   // +8 pad: frag-read stride 80B -> 2-way banks (free)
  __shared__ __align__(16) u16 Bsm[128][40];
  int tid = threadIdx.x, lane = tid & 63, wid = tid >> 6;
  int wr = wid >> 1, wc = wid & 1;
  int l16 = lane & 15, lhi = lane >> 4;
  size_t brow = (size_t)blockIdx.y * 128, bcol = (size_t)blockIdx.x * 128;
  const f32x4 vz = {0.f, 0.f, 0.f, 0.f};
  f32x4 acc[4][4];
#pragma unroll
  for (int m = 0; m < 4; m++)
#pragma unroll
    for (int n = 0; n < 4; n++) acc[m][n] = vz;
  int r = tid >> 2, kk = (tid & 3) * 8;
  const u16* Ab = A + (brow + r) * (size_t)K + kk;
  const u16* Bb = Bt + (bcol + r) * (size_t)K + kk;
  for (int kt = 0; kt < K; kt += 32){
    u32x4 a0 = *(const u32x4*)(Ab + kt);
    u32x4 a1 = *(const u32x4*)(Ab + (size_t)64 * K + kt);
    u32x4 b0 = *(const u32x4*)(Bb + kt);
    u32x4 b1 = *(const u32x4*)(Bb + (size_t)64 * K + kt);
    __syncthreads();
    *(u32x4*)&Asm[r][kk]      = a0;
    *(u32x4*)&Asm[r + 64][kk] = a1;
    *(u32x4*)&Bsm[r][kk]      = b0;
    *(u32x4*)&Bsm[r + 64][kk] = b1;
    __syncthreads();
    bf16x8 af[4], bfr[4];
#pragma unroll
    for (int m = 0; m < 4; m++) af[m]  = *(const bf16x8*)&Asm[wr*64 + m*16 + l16][lhi*8];
#pragma unroll
    for (int n = 0; n < 4; n++) bfr[n] = *(const bf16x8*)&Bsm[wc*64 + n*16 + l16][lhi*8];
#pragma unroll
    for (int m = 0; m < 4; m++)
#pragma unroll
      for (int n = 0; n < 4; n++) acc[m][n] = mfma16(af[m], bfr[n], acc[m][n]);
  }
  int rbase = wr*64 + lhi*4, cbase = wc*64 + l16;
#pragma unroll
  for (int m = 0; m < 4; m++)
#pragma unroll
    for (int n = 0; n < 4; n++)
#pragma unroll
      for (int i = 0; i < 4; i++){
        size_t row = brow + rbase + m*16 + i;
        size_t col = bcol + cbase + n*16;
        if (OUTBF) ((u16*)Cv)[row * (size_t)N + col] = f2bf(acc[m][n][i]);
        else       ((float*)Cv)[row * (size_t)N + col] = acc[m][n][i];
      }
}

// ---------------- RMSNorm + RoPE: qkv bf16 -> Q[h][t][d], K[h][t][d] (scale folded into Q) ----------------
__global__ __launch_bounds__(256) void k_rmsrope(const u16* __restrict__ qkv, const float* __restrict__ cosp,
                                                 const float* __restrict__ sinp, const float* __restrict__ qw,
                                                 const float* __restrict__ kw, u16* __restrict__ Qr,
                                                 u16* __restrict__ Kr){
  int t = blockIdx.x;
  int lane = threadIdx.x & 63, w = threadIdx.x >> 6;
  int hh = blockIdx.y * 4 + w;          // 0..39: 32 q heads + 8 k heads
  bool isq = hh < NQH;
  int hl = isq ? hh : hh - NQH;
  const u16* src = qkv + (size_t)t * QKVN + (isq ? hl * HD : NQH * HD + hl * HD);
  unsigned u = *(const unsigned*)(src + 2 * lane);       // d = 2*lane, 2*lane+1
  float x0 = bf2f((u16)(u & 0xffffu)), x1 = bf2f((u16)(u >> 16));
  float ss = x0 * x0 + x1 * x1;
#pragma unroll
  for (int m = 1; m < 64; m <<= 1) ss += __shfl_xor(ss, m);
  float rs = rsqrtf(ss * (1.f / HD) + 1e-6f);
  const float* wp = isq ? qw : kw;
  float w0 = wp[2 * lane], w1 = wp[2 * lane + 1];
  float xn0 = x0 * rs * w0, xn1 = x1 * rs * w1;
  float p0 = __shfl_xor(xn0, 32), p1 = __shfl_xor(xn1, 32);  // rotate-half partner
  int j0 = (2 * lane) & 63;
  float c0 = cosp[t * 64 + j0], c1 = cosp[t * 64 + j0 + 1];
  float s0 = sinp[t * 64 + j0], s1 = sinp[t * 64 + j0 + 1];
  float o0, o1;
  if (lane < 32){ o0 = xn0 * c0 - p0 * s0; o1 = xn1 * c1 - p1 * s1; }
  else          { o0 = xn0 * c0 + p0 * s0; o1 = xn1 * c1 + p1 * s1; }
  if (isq){ o0 *= 0.08838834764831845f; o1 *= 0.08838834764831845f; }  // D^-0.5
  u16* dst = isq ? (Qr + ((size_t)hl * SEQ + t) * HD) : (Kr + ((size_t)hl * SEQ + t) * HD);
  *(unsigned*)(dst + 2 * lane) = (unsigned)f2bf(o0) | ((unsigned)f2bf(o1) << 16);
}

// ---------------- V slice of qkv -> VT[h][d][t] bf16 ----------------
__global__ void k_vt(const u16* __restrict__ qkv, u16* __restrict__ VT){
  __shared__ u16 t[32][33];
  int t0 = blockIdx.x * 32, d0 = blockIdx.y * 32, hv = blockIdx.z;
  int tx = threadIdx.x, ty = threadIdx.y;
#pragma unroll
  for (int i = 0; i < 32; i += 8)
    t[ty + i][tx] = qkv[(size_t)(t0 + ty + i) * QKVN + (NQH + NKVH) * HD + hv * HD + d0 + tx];
  __syncthreads();
#pragma unroll
  for (int i = 0; i < 32; i += 8)
    VT[((size_t)hv * HD + d0 + ty + i) * SEQ + t0 + tx] = t[tx][ty + i];
}

// ---------------- causal GQA flash attention ----------------
// block: 128 q rows of one head; 4 waves x 32 rows; KV tiles of 64.
__global__ __launch_bounds__(256) void k_attn(const u16* __restrict__ Q, const u16* __restrict__ Kg,
                                              const u16* __restrict__ VTg, u16* __restrict__ AO){
  __shared__ __align__(16) u16 Ksm[64][136];    // [kv][d]  stride 272B -> 2-way banks
  __shared__ __align__(16) u16 VTsm[128][72];   // [d][kv]  stride 144B -> 2-way banks
  __shared__ __align__(16) u16 Psm[4][32][72];  // per-wave P tile [q][kv]
  int tid = threadIdx.x, lane = tid & 63, wid = tid >> 6;
  int l16 = lane & 15, lhi = lane >> 4;
  int qt0 = blockIdx.x * 128;
  int hq = blockIdx.y, hkv = hq >> 2;
  const u16* Kh = Kg  + (size_t)hkv * SEQ * HD;
  const u16* Vh = VTg + (size_t)hkv * HD * SEQ;

  // hoist Q fragments (rows = qt0 + wid*32 + m*16 + l16)
  bf16x8 qf[2][4];
#pragma unroll
  for (int m = 0; m < 2; m++)
#pragma unroll
    for (int ks = 0; ks < 4; ks++)
      qf[m][ks] = *(const bf16x8*)(Q + ((size_t)hq * SEQ + qt0 + wid*32 + m*16 + l16) * HD + ks*32 + lhi*8);

  const f32x4 vz = {0.f, 0.f, 0.f, 0.f};
  f32x4 o[2][8];
  float mrow[2][4], lrow[2][4];
#pragma unroll
  for (int m = 0; m < 2; m++){
#pragma unroll
    for (int n = 0; n < 8; n++) o[m][n] = vz;
#pragma unroll
    for (int i = 0; i < 4; i++){ mrow[m][i] = -1e30f; lrow[m][i] = 0.f; }
  }

  int qmaxw = qt0 + wid*32 + 31;
  int ntiles = (qt0 + 128) >> 6;
  for (int kt = 0; kt < ntiles; kt++){
    int kt0 = kt << 6;
    __syncthreads();  // previous PV done before restage
    {
      int rr = tid >> 4, dc = (tid & 15) * 8;
#pragma unroll
      for (int p = 0; p < 4; p++)
        *(u32x4*)&Ksm[rr + p*16][dc] = *(const u32x4*)(Kh + (size_t)(kt0 + rr + p*16) * HD + dc);
      int dd = tid >> 3, tc = (tid & 7) * 8;
#pragma unroll
      for (int p = 0; p < 4; p++)
        *(u32x4*)&VTsm[dd + p*32][tc] = *(const u32x4*)(Vh + (size_t)(dd + p*32) * SEQ + kt0 + tc);
    }
    __syncthreads();
    bool active = (kt0 <= qmaxw);
    if (active){
      f32x4 s[2][4];
#pragma unroll
      for (int m = 0; m < 2; m++)
#pragma unroll
        for (int n = 0; n < 4; n++) s[m][n] = vz;
#pragma unroll
      for (int n = 0; n < 4; n++)
#pragma unroll
        for (int ks = 0; ks < 4; ks++){
          bf16x8 kf = *(const bf16x8*)&Ksm[n*16 + l16][ks*32 + lhi*8];
#pragma unroll
          for (int m = 0; m < 2; m++) s[m][n] = mfma16(qf[m][ks], kf, s[m][n]);
        }
      if (kt0 + 63 > qt0 + wid*32){  // diagonal tile: causal mask
#pragma unroll
        for (int m = 0; m < 2; m++)
#pragma unroll
          for (int n = 0; n < 4; n++)
#pragma unroll
            for (int i = 0; i < 4; i++){
              int kq = kt0 + n*16 + l16;
              int qq = qt0 + wid*32 + m*16 + lhi*4 + i;
              if (kq > qq) s[m][n][i] = -1e30f;
            }
      }
      // online softmax (rows live in 16-lane groups sharing lhi)
#pragma unroll
      for (int m = 0; m < 2; m++)
#pragma unroll
        for (int i = 0; i < 4; i++){
          float tm = fmaxf(fmaxf(s[m][0][i], s[m][1][i]), fmaxf(s[m][2][i], s[m][3][i]));
          tm = fmaxf(tm, __shfl_xor(tm, 1));
          tm = fmaxf(tm, __shfl_xor(tm, 2));
          tm = fmaxf(tm, __shfl_xor(tm, 4));
          tm = fmaxf(tm, __shfl_xor(tm, 8));
          float nm = fmaxf(mrow[m][i], tm);
          float sc = __expf(mrow[m][i] - nm);
          mrow[m][i] = nm;
          float rsum = 0.f;
#pragma unroll
          for (int n = 0; n < 4; n++){
            float p = __expf(s[m][n][i] - nm);
            s[m][n][i] = p;
            rsum += p;
          }
          rsum += __shfl_xor(rsum, 1);
          rsum += __shfl_xor(rsum, 2);
          rsum += __shfl_xor(rsum, 4);
          rsum += __shfl_xor(rsum, 8);
          lrow[m][i] = lrow[m][i] * sc + rsum;
#pragma unroll
          for (int n = 0; n < 8; n++) o[m][n][i] *= sc;
        }
      // P (D-layout) -> LDS for A-fragment reads
#pragma unroll
      for (int m = 0; m < 2; m++)
#pragma unroll
        for (int n = 0; n < 4; n++)
#pragma unroll
          for (int i = 0; i < 4; i++)
            Psm[wid][m*16 + lhi*4 + i][n*16 + l16] = f2bf(s[m][n][i]);
    }
    __syncthreads();  // P visible
    if (active){
#pragma unroll
      for (int ks = 0; ks < 2; ks++){
        bf16x8 pa[2];
#pragma unroll
        for (int m = 0; m < 2; m++)
          pa[m] = *(const bf16x8*)&Psm[wid][m*16 + l16][ks*32 + lhi*8];
#pragma unroll
        for (int n = 0; n < 8; n++){
          bf16x8 vb = *(const bf16x8*)&VTsm[n*16 + l16][ks*32 + lhi*8];
#pragma unroll
          for (int m = 0; m < 2; m++) o[m][n] = mfma16(pa[m], vb, o[m][n]);
        }
      }
    }
  }
  // epilogue: O /= l, write bf16 to AO[t][hq*128 + d]
#pragma unroll
  for (int m = 0; m < 2; m++){
    float inv[4];
#pragma unroll
    for (int i = 0; i < 4; i++) inv[i] = 1.f / lrow[m][i];
#pragma unroll
    for (int n = 0; n < 8; n++)
#pragma unroll
      for (int i = 0; i < 4; i++){
        int trow = qt0 + wid*32 + m*16 + lhi*4 + i;
        AO[(size_t)trow * HID + hq * HD + n*16 + l16] = f2bf(o[m][n][i] * inv[i]);
      }
  }
}

// ---------------- launch ----------------
extern "C" void kernel_launch(void* const* d_in, const int* in_sizes, int n_in,
                              void* d_out, int out_size, void* d_ws, size_t ws_size,
                              hipStream_t stream){
  const float* hs   = (const float*)d_in[0];
  const float* cosp = (const float*)d_in[1];
  const float* sinp = (const float*)d_in[2];
  const float* wqkv = (const float*)d_in[3];
  const float* wo   = (const float*)d_in[4];
  const float* qw   = (const float*)d_in[5];
  const float* kw   = (const float*)d_in[6];
  float* out = (float*)d_out;
  char* ws = (char*)d_ws;
  // workspace layout (128 MB total); WOT reuses XB/WQKVT region after GEMM1
  u16* XB    = (u16*)(ws + 0);            // 16.8 MB  X bf16 [2048][4096]
  u16* WQKVT = (u16*)(ws + 16777216);     // 50.3 MB  WqkvT bf16 [6144][4096]
  u16* WOT   = (u16*)(ws + 0);            // 33.6 MB  WoT bf16 [4096][4096] (after GEMM1)
  u16* QKV   = (u16*)(ws + 67108864);     // 25.2 MB  qkv bf16 [2048][6144]
  u16* QR    = (u16*)(ws + 92274688);     // 16.8 MB  Q bf16 [32][2048][128]
  u16* KR    = (u16*)(ws + 109051904);    //  4.2 MB  K bf16 [8][2048][128]
  u16* VTB   = (u16*)(ws + 113246208);    //  4.2 MB  VT bf16 [8][128][2048]
  u16* AOB   = (u16*)(ws + 117440512);    // 16.8 MB  attn out bf16 [2048][4096]

  k_cvt<<<(SEQ * HID / 4 + 255) / 256, 256, 0, stream>>>(hs, XB, SEQ * HID / 4);
  k_transpose_cvt<<<dim3(QKVN / 32, HID / 32), dim3(32, 8), 0, stream>>>(wqkv, WQKVT, HID, QKVN);
  k_gemm<1><<<dim3(QKVN / 128, SEQ / 128), 256, 0, stream>>>(XB, WQKVT, QKV, SEQ, QKVN, HID);
  k_transpose_cvt<<<dim3(HID / 32, HID / 32), dim3(32, 8), 0, stream>>>(wo, WOT, HID, HID);
  k_rmsrope<<<dim3(SEQ, 10), 256, 0, stream>>>(QKV, cosp, sinp, qw, kw, QR, KR);
  k_vt<<<dim3(SEQ / 32, HD / 32, NKVH), dim3(32, 8), 0, stream>>>(QKV, VTB);
  k_attn<<<dim3(SEQ / 128, NQH), 256, 0, stream>>>(QR, KR, VTB, AOB);
  k_gemm<0><<<dim3(HID / 128, SEQ / 128), 256, 0, stream>>>(AOB, WOT, out, SEQ, HID, HID);
}

// Round 2
// 523.017 us; speedup vs baseline: 1.0427x; 1.0427x over previous
//
#include <hip/hip_runtime.h>
#include <stdint.h>

#define SEQ   2048
#define HID   4096
#define NQH   32
#define NKVH  8
#define HD    128
#define QKVN  6144   // (32 + 2*8) * 128

typedef uint16_t u16;
typedef __attribute__((ext_vector_type(8))) short bf16x8;
typedef __attribute__((ext_vector_type(4))) float f32x4;
typedef __attribute__((ext_vector_type(4))) unsigned int u32x4;

static __device__ __forceinline__ float bf2f(u16 h){
  union { float f; unsigned int u; } v; v.u = ((unsigned int)h) << 16; return v.f;
}
static __device__ __forceinline__ u16 f2bf(float f){
  unsigned int u = __float_as_uint(f);
  return (u16)((u + 0x7fffu + ((u >> 16) & 1u)) >> 16);  // RNE, finite inputs only
}
static __device__ __forceinline__ f32x4 mfma16(bf16x8 a, bf16x8 b, f32x4 c){
  return __builtin_amdgcn_mfma_f32_16x16x32_bf16(a, b, c, 0, 0, 0);
}
static __device__ __forceinline__ void gload16(const void* g, void* l){
  __builtin_amdgcn_global_load_lds((const __attribute__((address_space(1))) void*)g,
                                   (__attribute__((address_space(3))) void*)l, 16, 0, 0);
}

// ---------------- fp32 -> bf16 elementwise (n4 = n/4) ----------------
__global__ void k_cvt(const float* __restrict__ src, u16* __restrict__ dst, int n4){
  int i = blockIdx.x * blockDim.x + threadIdx.x;
  if (i >= n4) return;
  float4 v = ((const float4*)src)[i];
  uint2 o;
  o.x = (unsigned)f2bf(v.x) | ((unsigned)f2bf(v.y) << 16);
  o.y = (unsigned)f2bf(v.z) | ((unsigned)f2bf(v.w) << 16);
  ((uint2*)dst)[i] = o;
}

// ---------------- src[K][N] fp32 -> dst[N][K] bf16 (transpose-convert) ----------------
__global__ void k_transpose_cvt(const float* __restrict__ src, u16* __restrict__ dst, int K, int N){
  __shared__ float t[32][33];
  int n0 = blockIdx.x * 32, k0 = blockIdx.y * 32;
  int tx = threadIdx.x, ty = threadIdx.y;
#pragma unroll
  for (int i = 0; i < 32; i += 8)
    t[ty + i][tx] = src[(size_t)(k0 + ty + i) * N + n0 + tx];
  __syncthreads();
#pragma unroll
  for (int i = 0; i < 32; i += 8)
    dst[(size_t)(n0 + ty + i) * K + k0 + tx] = f2bf(t[tx][ty + i]);
}

// ---------------- C[M][N] = A[M][K] @ Bt[N][K]^T, bf16 in, OUTBF? bf16 : fp32 out ----------------
// m97 structure: 128x128 tile, BK=32, global_load_lds width=16 into linear LDS,
// 4 waves (2x2), each wave 4x4 frags of 16x16x32 MFMA, 2 barriers/K-step.
template<int OUTBF>
__global__ __launch_bounds__(256) void k_gemm(const u16* __restrict__ A, const u16* __restrict__ Bt,
                                              void* __restrict__ Cv, int M, int N, int K){
  __shared__ __align__(16) u16 Asm[128][32];   // linear: global_load_lds dest must be unpadded
  __shared__ __align__(16) u16 Bsm[128][32];
  int tid = threadIdx.x, lane = tid & 63, wid = tid >> 6;
  int wr = wid >> 1, wc = wid & 1;
  int l16 = lane & 15, lhi = lane >> 4;
  size_t brow = (size_t)blockIdx.y * 128, bcol = (size_t)blockIdx.x * 128;
  const f32x4 vz = {0.f, 0.f, 0.f, 0.f};
  f32x4 acc[4][4];
#pragma unroll
  for (int m = 0; m < 4; m++)
#pragma unroll
    for (int n = 0; n < 4; n++) acc[m][n] = vz;
  // staging: wave w covers rows w*32..w*32+31 of each tile, 2 issues of 16 rows
  int srow = wid * 32 + (lane >> 2);       // + issue*16
  int scol = (lane & 3) * 8;               // element offset in row
  const u16* Ag = A + (brow + srow) * (size_t)K + scol;
  const u16* Bg = Bt + (bcol + srow) * (size_t)K + scol;
  u16* Al0 = &Asm[wid * 32][0];
  u16* Al1 = &Asm[wid * 32 + 16][0];
  u16* Bl0 = &Bsm[wid * 32][0];
  u16* Bl1 = &Bsm[wid * 32 + 16][0];
  for (int kt = 0; kt < K; kt += 32){
    __syncthreads();  // all waves done reading prev tile
    gload16(Ag + kt, Al0);
    gload16(Ag + (size_t)16 * K + kt, Al1);
    gload16(Bg + kt, Bl0);
    gload16(Bg + (size_t)16 * K + kt, Bl1);
    __syncthreads();  // vmcnt drained -> tile visible
    bf16x8 af[4], bfr[4];
#pragma unroll
    for (int m = 0; m < 4; m++) af[m]  = *(const bf16x8*)&Asm[wr*64 + m*16 + l16][lhi*8];
#pragma unroll
    for (int n = 0; n < 4; n++) bfr[n] = *(const bf16x8*)&Bsm[wc*64 + n*16 + l16][lhi*8];
#pragma unroll
    for (int m = 0; m < 4; m++)
#pragma unroll
      for (int n = 0; n < 4; n++) acc[m][n] = mfma16(af[m], bfr[n], acc[m][n]);
  }
  int rbase = wr*64 + lhi*4, cbase = wc*64 + l16;
#pragma unroll
  for (int m = 0; m < 4; m++)
#pragma unroll
    for (int n = 0; n < 4; n++)
#pragma unroll
      for (int i = 0; i < 4; i++){
        size_t row = brow + rbase + m*16 + i;
        size_t col = bcol + cbase + n*16;
        if (OUTBF) ((u16*)Cv)[row * (size_t)N + col] = f2bf(acc[m][n][i]);
        else       ((float*)Cv)[row * (size_t)N + col] = acc[m][n][i];
      }
}

// ---------------- RMSNorm + RoPE: qkv bf16 -> Q[h][t][d], K[h][t][d] (scale folded into Q) ----------------
__global__ __launch_bounds__(256) void k_rmsrope(const u16* __restrict__ qkv, const float* __restrict__ cosp,
                                                 const float* __restrict__ sinp, const float* __restrict__ qw,
                                                 const float* __restrict__ kw, u16* __restrict__ Qr,
                                                 u16* __restrict__ Kr){
  int t = blockIdx.x;
  int lane = threadIdx.x & 63, w = threadIdx.x >> 6;
  int hh = blockIdx.y * 4 + w;          // 0..39: 32 q heads + 8 k heads
  bool isq = hh < NQH;
  int hl = isq ? hh : hh - NQH;
  const u16* src = qkv + (size_t)t * QKVN + (isq ? hl * HD : NQH * HD + hl * HD);
  unsigned u = *(const unsigned*)(src + 2 * lane);       // d = 2*lane, 2*lane+1
  float x0 = bf2f((u16)(u & 0xffffu)), x1 = bf2f((u16)(u >> 16));
  float ss = x0 * x0 + x1 * x1;
#pragma unroll
  for (int m = 1; m < 64; m <<= 1) ss += __shfl_xor(ss, m);
  float rs = rsqrtf(ss * (1.f / HD) + 1e-6f);
  const float* wp = isq ? qw : kw;
  float w0 = wp[2 * lane], w1 = wp[2 * lane + 1];
  float xn0 = x0 * rs * w0, xn1 = x1 * rs * w1;
  float p0 = __shfl_xor(xn0, 32), p1 = __shfl_xor(xn1, 32);  // rotate-half partner
  int j0 = (2 * lane) & 63;
  float c0 = cosp[t * 64 + j0], c1 = cosp[t * 64 + j0 + 1];
  float s0 = sinp[t * 64 + j0], s1 = sinp[t * 64 + j0 + 1];
  float o0, o1;
  if (lane < 32){ o0 = xn0 * c0 - p0 * s0; o1 = xn1 * c1 - p1 * s1; }
  else          { o0 = xn0 * c0 + p0 * s0; o1 = xn1 * c1 + p1 * s1; }
  if (isq){ o0 *= 0.08838834764831845f; o1 *= 0.08838834764831845f; }  // D^-0.5
  u16* dst = isq ? (Qr + ((size_t)hl * SEQ + t) * HD) : (Kr + ((size_t)hl * SEQ + t) * HD);
  *(unsigned*)(dst + 2 * lane) = (unsigned)f2bf(o0) | ((unsigned)f2bf(o1) << 16);
}

// ---------------- V slice of qkv -> VT[h][d][t] bf16 ----------------
__global__ void k_vt(const u16* __restrict__ qkv, u16* __restrict__ VT){
  __shared__ u16 t[32][33];
  int t0 = blockIdx.x * 32, d0 = blockIdx.y * 32, hv = blockIdx.z;
  int tx = threadIdx.x, ty = threadIdx.y;
#pragma unroll
  for (int i = 0; i < 32; i += 8)
    t[ty + i][tx] = qkv[(size_t)(t0 + ty + i) * QKVN + (NQH + NKVH) * HD + hv * HD + d0 + tx];
  __syncthreads();
#pragma unroll
  for (int i = 0; i < 32; i += 8)
    VT[((size_t)hv * HD + d0 + ty + i) * SEQ + t0 + tx] = t[tx][ty + i];
}

// ---------------- causal GQA flash attention, balanced-pair q-tiles ----------------
// 1D grid of 512 blocks. Block -> (kv head, q head, pair j) via XCD swizzle so each
// XCD owns one kv-head group (K+V = 1MB, L2-resident). Each block: two 64-row q-tiles
// j (rows 64j..) and 31-j; every block does exactly 33 tile-units of MFMA work.
// 4 waves x (16 low rows + 16 high rows). K staged in LDS (4x reuse); V read from L2.
__global__ __launch_bounds__(256) void k_attn(const u16* __restrict__ Q, const u16* __restrict__ Kg,
                                              const u16* __restrict__ VTg, u16* __restrict__ AO){
  __shared__ __align__(16) u16 Ksm[64][136];    // [kv][d]  stride 272B
  __shared__ __align__(16) u16 Psm[4][32][72];  // per-wave P [m*16+row][kv]
  int tid = threadIdx.x, lane = tid & 63, wid = tid >> 6;
  int l16 = lane & 15, lhi = lane >> 4;
  int bid = blockIdx.x;
  int kvg = bid & 7, rr = bid >> 3;          // xcd-swizzle: kv-group = bid%8
  int hq = kvg * 4 + (rr >> 4);
  int j = rr & 15;
  int tb[2] = { j * 64, (31 - j) * 64 };     // low / high tile base rows
  const u16* Kh = Kg  + (size_t)kvg * SEQ * HD;
  const u16* Vh = VTg + (size_t)kvg * HD * SEQ;
  const u16* Qh = Q   + (size_t)hq * SEQ * HD;

  bf16x8 qf[2][4];
#pragma unroll
  for (int m = 0; m < 2; m++)
#pragma unroll
    for (int ks = 0; ks < 4; ks++)
      qf[m][ks] = *(const bf16x8*)(Qh + (size_t)(tb[m] + wid*16 + l16) * HD + ks*32 + lhi*8);

  const f32x4 vz = {0.f, 0.f, 0.f, 0.f};
  f32x4 o[2][8];
  float mrow[2][4], lrow[2][4];
#pragma unroll
  for (int m = 0; m < 2; m++){
#pragma unroll
    for (int n = 0; n < 8; n++) o[m][n] = vz;
#pragma unroll
    for (int i = 0; i < 4; i++){ mrow[m][i] = -1e30f; lrow[m][i] = 0.f; }
  }

  int nt = 32 - j;   // high tile range; low tile active for kt <= j
  for (int kt = 0; kt < nt; kt++){
    int kt0 = kt << 6;
    __syncthreads();  // prev Ksm/Psm reads complete
    {
      int sr = tid >> 4, sc = (tid & 15) * 8;
#pragma unroll
      for (int p = 0; p < 4; p++)
        *(u32x4*)&Ksm[sr + p*16][sc] = *(const u32x4*)(Kh + (size_t)(kt0 + sr + p*16) * HD + sc);
    }
    __syncthreads();  // Ksm visible
    bool act0 = (kt <= j);
    f32x4 s[2][4];
#pragma unroll
    for (int m = 0; m < 2; m++)
#pragma unroll
      for (int n = 0; n < 4; n++) s[m][n] = vz;
#pragma unroll
    for (int n = 0; n < 4; n++)
#pragma unroll
      for (int ks = 0; ks < 4; ks++){
        bf16x8 kf = *(const bf16x8*)&Ksm[n*16 + l16][ks*32 + lhi*8];
        s[1][n] = mfma16(qf[1][ks], kf, s[1][n]);
        if (act0) s[0][n] = mfma16(qf[0][ks], kf, s[0][n]);
      }
#pragma unroll
    for (int m = 0; m < 2; m++){
      if (m == 0 && !act0) continue;
      if (kt0 + 63 > tb[m] + wid*16){  // diagonal tile for this wave's rows
#pragma unroll
        for (int n = 0; n < 4; n++)
#pragma unroll
          for (int i = 0; i < 4; i++){
            int kq = kt0 + n*16 + l16;
            int qq = tb[m] + wid*16 + lhi*4 + i;
            if (kq > qq) s[m][n][i] = -1e30f;
          }
      }
      // online softmax (rows live in 16-lane groups sharing lhi)
#pragma unroll
      for (int i = 0; i < 4; i++){
        float tm = fmaxf(fmaxf(s[m][0][i], s[m][1][i]), fmaxf(s[m][2][i], s[m][3][i]));
        tm = fmaxf(tm, __shfl_xor(tm, 1));
        tm = fmaxf(tm, __shfl_xor(tm, 2));
        tm = fmaxf(tm, __shfl_xor(tm, 4));
        tm = fmaxf(tm, __shfl_xor(tm, 8));
        float nm = fmaxf(mrow[m][i], tm);
        float sc = __expf(mrow[m][i] - nm);
        mrow[m][i] = nm;
        float rsum = 0.f;
#pragma unroll
        for (int n = 0; n < 4; n++){
          float p = __expf(s[m][n][i] - nm);
          s[m][n][i] = p;
          rsum += p;
        }
        rsum += __shfl_xor(rsum, 1);
        rsum += __shfl_xor(rsum, 2);
        rsum += __shfl_xor(rsum, 4);
        rsum += __shfl_xor(rsum, 8);
        lrow[m][i] = lrow[m][i] * sc + rsum;
#pragma unroll
        for (int n = 0; n < 8; n++) o[m][n][i] *= sc;
      }
      // P (D-layout) -> LDS for A-fragment reads
#pragma unroll
      for (int n = 0; n < 4; n++)
#pragma unroll
        for (int i = 0; i < 4; i++)
          Psm[wid][m*16 + lhi*4 + i][n*16 + l16] = f2bf(s[m][n][i]);
    }
    __syncthreads();  // Psm visible
#pragma unroll
    for (int ks = 0; ks < 2; ks++){
      bf16x8 pa1 = *(const bf16x8*)&Psm[wid][16 + l16][ks*32 + lhi*8];
      bf16x8 pa0;
      if (act0) pa0 = *(const bf16x8*)&Psm[wid][l16][ks*32 + lhi*8];
#pragma unroll
      for (int n = 0; n < 8; n++){
        bf16x8 vb = *(const bf16x8*)(Vh + (size_t)(n*16 + l16) * SEQ + kt0 + ks*32 + lhi*8);
        o[1][n] = mfma16(pa1, vb, o[1][n]);
        if (act0) o[0][n] = mfma16(pa0, vb, o[0][n]);
      }
    }
  }
  // epilogue: O /= l, write bf16 to AO[t][hq*128 + d]
#pragma unroll
  for (int m = 0; m < 2; m++){
    float inv[4];
#pragma unroll
    for (int i = 0; i < 4; i++) inv[i] = 1.f / lrow[m][i];
#pragma unroll
    for (int n = 0; n < 8; n++)
#pragma unroll
      for (int i = 0; i < 4; i++){
        int trow = tb[m] + wid*16 + lhi*4 + i;
        AO[(size_t)trow * HID + hq * HD + n*16 + l16] = f2bf(o[m][n][i] * inv[i]);
      }
  }
}

// ---------------- launch ----------------
extern "C" void kernel_launch(void* const* d_in, const int* in_sizes, int n_in,
                              void* d_out, int out_size, void* d_ws, size_t ws_size,
                              hipStream_t stream){
  const float* hs   = (const float*)d_in[0];
  const float* cosp = (const float*)d_in[1];
  const float* sinp = (const float*)d_in[2];
  const float* wqkv = (const float*)d_in[3];
  const float* wo   = (const float*)d_in[4];
  const float* qw   = (const float*)d_in[5];
  const float* kw   = (const float*)d_in[6];
  float* out = (float*)d_out;
  char* ws = (char*)d_ws;
  // workspace layout (128 MB total); WOT reuses XB/WQKVT region after GEMM1
  u16* XB    = (u16*)(ws + 0);            // 16.8 MB  X bf16 [2048][4096]
  u16* WQKVT = (u16*)(ws + 16777216);     // 50.3 MB  WqkvT bf16 [6144][4096]
  u16* WOT   = (u16*)(ws + 0);            // 33.6 MB  WoT bf16 [4096][4096] (after GEMM1)
  u16* QKV   = (u16*)(ws + 67108864);     // 25.2 MB  qkv bf16 [2048][6144]
  u16* QR    = (u16*)(ws + 92274688);     // 16.8 MB  Q bf16 [32][2048][128]
  u16* KR    = (u16*)(ws + 109051904);    //  4.2 MB  K bf16 [8][2048][128]
  u16* VTB   = (u16*)(ws + 113246208);    //  4.2 MB  VT bf16 [8][128][2048]
  u16* AOB   = (u16*)(ws + 117440512);    // 16.8 MB  attn out bf16 [2048][4096]

  k_cvt<<<(SEQ * HID / 4 + 255) / 256, 256, 0, stream>>>(hs, XB, SEQ * HID / 4);
  k_transpose_cvt<<<dim3(QKVN / 32, HID / 32), dim3(32, 8), 0, stream>>>(wqkv, WQKVT, HID, QKVN);
  k_gemm<1><<<dim3(QKVN / 128, SEQ / 128), 256, 0, stream>>>(XB, WQKVT, QKV, SEQ, QKVN, HID);
  k_transpose_cvt<<<dim3(HID / 32, HID / 32), dim3(32, 8), 0, stream>>>(wo, WOT, HID, HID);
  k_rmsrope<<<dim3(SEQ, 10), 256, 0, stream>>>(QKV, cosp, sinp, qw, kw, QR, KR);
  k_vt<<<dim3(SEQ / 32, HD / 32, NKVH), dim3(32, 8), 0, stream>>>(QKV, VTB);
  k_attn<<<512, 256, 0, stream>>>(QR, KR, VTB, AOB);
  k_gemm<0><<<dim3(HID / 128, SEQ / 128), 256, 0, stream>>>(AOB, WOT, out, SEQ, HID, HID);
}

// Round 3
// 397.582 us; speedup vs baseline: 1.3716x; 1.3155x over previous
//
#include <hip/hip_runtime.h>
#include <stdint.h>

#define SEQ   2048
#define HID   4096
#define NQH   32
#define NKVH  8
#define HD    128
#define QKVN  6144   // (32 + 2*8) * 128

typedef uint16_t u16;
typedef __attribute__((ext_vector_type(8))) short bf16x8;
typedef __attribute__((ext_vector_type(4))) float f32x4;
typedef __attribute__((ext_vector_type(4))) unsigned int u32x4;

static __device__ __forceinline__ float bf2f(u16 h){
  union { float f; unsigned int u; } v; v.u = ((unsigned int)h) << 16; return v.f;
}
static __device__ __forceinline__ u16 f2bf(float f){
  unsigned int u = __float_as_uint(f);
  return (u16)((u + 0x7fffu + ((u >> 16) & 1u)) >> 16);  // RNE, finite inputs only
}
static __device__ __forceinline__ f32x4 mfma16(bf16x8 a, bf16x8 b, f32x4 c){
  return __builtin_amdgcn_mfma_f32_16x16x32_bf16(a, b, c, 0, 0, 0);
}
static __device__ __forceinline__ void gload16(const void* g, void* l){
  __builtin_amdgcn_global_load_lds((const __attribute__((address_space(1))) void*)g,
                                   (__attribute__((address_space(3))) void*)l, 16, 0, 0);
}

// ---------------- fp32 -> bf16 elementwise (n4 = n/4) ----------------
__global__ void k_cvt(const float* __restrict__ src, u16* __restrict__ dst, int n4){
  int i = blockIdx.x * blockDim.x + threadIdx.x;
  if (i >= n4) return;
  float4 v = ((const float4*)src)[i];
  uint2 o;
  o.x = (unsigned)f2bf(v.x) | ((unsigned)f2bf(v.y) << 16);
  o.y = (unsigned)f2bf(v.z) | ((unsigned)f2bf(v.w) << 16);
  ((uint2*)dst)[i] = o;
}

// ---------------- src[K][N] fp32 -> dst[N][K] bf16 (transpose-convert) ----------------
__global__ void k_transpose_cvt(const float* __restrict__ src, u16* __restrict__ dst, int K, int N){
  __shared__ float t[32][33];
  int n0 = blockIdx.x * 32, k0 = blockIdx.y * 32;
  int tx = threadIdx.x, ty = threadIdx.y;
#pragma unroll
  for (int i = 0; i < 32; i += 8)
    t[ty + i][tx] = src[(size_t)(k0 + ty + i) * N + n0 + tx];
  __syncthreads();
#pragma unroll
  for (int i = 0; i < 32; i += 8)
    dst[(size_t)(n0 + ty + i) * K + k0 + tx] = f2bf(t[tx][ty + i]);
}

// ---------------- C[M][N] = A[M][K] @ Bt[N][K]^T, bf16 in, OUTBF? bf16 : fp32 out ----------------
// m97 structure: 128x128 tile, BK=32, global_load_lds width=16 into linear LDS,
// 4 waves (2x2), each wave 4x4 frags of 16x16x32 MFMA, 2 barriers/K-step.
template<int OUTBF>
__global__ __launch_bounds__(256) void k_gemm(const u16* __restrict__ A, const u16* __restrict__ Bt,
                                              void* __restrict__ Cv, int M, int N, int K){
  __shared__ __align__(16) u16 Asm[128][32];   // linear: global_load_lds dest must be unpadded
  __shared__ __align__(16) u16 Bsm[128][32];
  int tid = threadIdx.x, lane = tid & 63, wid = tid >> 6;
  int wr = wid >> 1, wc = wid & 1;
  int l16 = lane & 15, lhi = lane >> 4;
  size_t brow = (size_t)blockIdx.y * 128, bcol = (size_t)blockIdx.x * 128;
  const f32x4 vz = {0.f, 0.f, 0.f, 0.f};
  f32x4 acc[4][4];
#pragma unroll
  for (int m = 0; m < 4; m++)
#pragma unroll
    for (int n = 0; n < 4; n++) acc[m][n] = vz;
  // staging: wave w covers rows w*32..w*32+31 of each tile, 2 issues of 16 rows
  int srow = wid * 32 + (lane >> 2);       // + issue*16
  int scol = (lane & 3) * 8;               // element offset in row
  const u16* Ag = A + (brow + srow) * (size_t)K + scol;
  const u16* Bg = Bt + (bcol + srow) * (size_t)K + scol;
  u16* Al0 = &Asm[wid * 32][0];
  u16* Al1 = &Asm[wid * 32 + 16][0];
  u16* Bl0 = &Bsm[wid * 32][0];
  u16* Bl1 = &Bsm[wid * 32 + 16][0];
  for (int kt = 0; kt < K; kt += 32){
    __syncthreads();  // all waves done reading prev tile
    gload16(Ag + kt, Al0);
    gload16(Ag + (size_t)16 * K + kt, Al1);
    gload16(Bg + kt, Bl0);
    gload16(Bg + (size_t)16 * K + kt, Bl1);
    __syncthreads();  // vmcnt drained -> tile visible
    bf16x8 af[4], bfr[4];
#pragma unroll
    for (int m = 0; m < 4; m++) af[m]  = *(const bf16x8*)&Asm[wr*64 + m*16 + l16][lhi*8];
#pragma unroll
    for (int n = 0; n < 4; n++) bfr[n] = *(const bf16x8*)&Bsm[wc*64 + n*16 + l16][lhi*8];
#pragma unroll
    for (int m = 0; m < 4; m++)
#pragma unroll
      for (int n = 0; n < 4; n++) acc[m][n] = mfma16(af[m], bfr[n], acc[m][n]);
  }
  int rbase = wr*64 + lhi*4, cbase = wc*64 + l16;
#pragma unroll
  for (int m = 0; m < 4; m++)
#pragma unroll
    for (int n = 0; n < 4; n++)
#pragma unroll
      for (int i = 0; i < 4; i++){
        size_t row = brow + rbase + m*16 + i;
        size_t col = bcol + cbase + n*16;
        if (OUTBF) ((u16*)Cv)[row * (size_t)N + col] = f2bf(acc[m][n][i]);
        else       ((float*)Cv)[row * (size_t)N + col] = acc[m][n][i];
      }
}

// ---------------- RMSNorm + RoPE: qkv bf16 -> Q[h][t][d], K[h][t][d] (scale folded into Q) ----------------
__global__ __launch_bounds__(256) void k_rmsrope(const u16* __restrict__ qkv, const float* __restrict__ cosp,
                                                 const float* __restrict__ sinp, const float* __restrict__ qw,
                                                 const float* __restrict__ kw, u16* __restrict__ Qr,
                                                 u16* __restrict__ Kr){
  int t = blockIdx.x;
  int lane = threadIdx.x & 63, w = threadIdx.x >> 6;
  int hh = blockIdx.y * 4 + w;          // 0..39: 32 q heads + 8 k heads
  bool isq = hh < NQH;
  int hl = isq ? hh : hh - NQH;
  const u16* src = qkv + (size_t)t * QKVN + (isq ? hl * HD : NQH * HD + hl * HD);
  unsigned u = *(const unsigned*)(src + 2 * lane);       // d = 2*lane, 2*lane+1
  float x0 = bf2f((u16)(u & 0xffffu)), x1 = bf2f((u16)(u >> 16));
  float ss = x0 * x0 + x1 * x1;
#pragma unroll
  for (int m = 1; m < 64; m <<= 1) ss += __shfl_xor(ss, m);
  float rs = rsqrtf(ss * (1.f / HD) + 1e-6f);
  const float* wp = isq ? qw : kw;
  float w0 = wp[2 * lane], w1 = wp[2 * lane + 1];
  float xn0 = x0 * rs * w0, xn1 = x1 * rs * w1;
  float p0 = __shfl_xor(xn0, 32), p1 = __shfl_xor(xn1, 32);  // rotate-half partner
  int j0 = (2 * lane) & 63;
  float c0 = cosp[t * 64 + j0], c1 = cosp[t * 64 + j0 + 1];
  float s0 = sinp[t * 64 + j0], s1 = sinp[t * 64 + j0 + 1];
  float o0, o1;
  if (lane < 32){ o0 = xn0 * c0 - p0 * s0; o1 = xn1 * c1 - p1 * s1; }
  else          { o0 = xn0 * c0 + p0 * s0; o1 = xn1 * c1 + p1 * s1; }
  if (isq){ o0 *= 0.08838834764831845f; o1 *= 0.08838834764831845f; }  // D^-0.5
  u16* dst = isq ? (Qr + ((size_t)hl * SEQ + t) * HD) : (Kr + ((size_t)hl * SEQ + t) * HD);
  *(unsigned*)(dst + 2 * lane) = (unsigned)f2bf(o0) | ((unsigned)f2bf(o1) << 16);
}

// ---------------- V slice of qkv -> VT[h][d][t] bf16 ----------------
__global__ void k_vt(const u16* __restrict__ qkv, u16* __restrict__ VT){
  __shared__ u16 t[32][33];
  int t0 = blockIdx.x * 32, d0 = blockIdx.y * 32, hv = blockIdx.z;
  int tx = threadIdx.x, ty = threadIdx.y;
#pragma unroll
  for (int i = 0; i < 32; i += 8)
    t[ty + i][tx] = qkv[(size_t)(t0 + ty + i) * QKVN + (NQH + NKVH) * HD + hv * HD + d0 + tx];
  __syncthreads();
#pragma unroll
  for (int i = 0; i < 32; i += 8)
    VT[((size_t)hv * HD + d0 + ty + i) * SEQ + t0 + tx] = t[tx][ty + i];
}

// ---------------- causal GQA flash attention ----------------
// 512 blocks (8 waves, 512 thr): one 128-row q-tile per block, longest-first.
// bid -> kvg=bid&7 (XCD L2 locality: K+V+4 Q heads = 3MB per XCD), J=15-(rr>>2) desc.
// K[64][128] and VT[128][64] double-buffered in LDS via global_load_lds with
// G21 XOR-swizzle (linear dest + inverse-swizzled source + swizzled ds_read).
// One barrier per KV tile; tile t+1 prefetch issued at trip t start.
__global__ __launch_bounds__(512, 2) void k_attn(const u16* __restrict__ Q, const u16* __restrict__ Kg,
                                                 const u16* __restrict__ VTg, u16* __restrict__ AO){
  __shared__ __align__(16) u16 Ksm[2][64][128];   // [buf][kv][d], 16B-granule swizzled
  __shared__ __align__(16) u16 Vsm[2][128][64];   // [buf][d][kv], swizzled
  __shared__ __align__(16) u16 Psm[8][16][72];    // per-wave P [q][kv]
  int tid = threadIdx.x, lane = tid & 63, wid = tid >> 6;
  int l16 = lane & 15, lhi = lane >> 4;
  int bid = blockIdx.x;
  int kvg = bid & 7, rr = bid >> 3;               // 64 blocks per kv-group
  int J = 15 - (rr >> 2);                         // longest-first
  int hq = kvg * 4 + (rr & 3);
  int qb = J * 128;
  const u16* Kh = Kg  + (size_t)kvg * SEQ * HD;
  const u16* Vh = VTg + (size_t)kvg * HD * SEQ;
  const u16* Qh = Q   + (size_t)hq * SEQ * HD;

  // Q fragments: wave owns rows qb + wid*16 .. +15
  bf16x8 qf[4];
#pragma unroll
  for (int ks = 0; ks < 4; ks++)
    qf[ks] = *(const bf16x8*)(Qh + (size_t)(qb + wid*16 + l16) * HD + ks*32 + lhi*8);

  const f32x4 vz = {0.f, 0.f, 0.f, 0.f};
  f32x4 o[8];
  float mrow[4], lrow[4];
#pragma unroll
  for (int n = 0; n < 8; n++) o[n] = vz;
#pragma unroll
  for (int i = 0; i < 4; i++){ mrow[i] = -1e30f; lrow[i] = 0.f; }

  // staging source pointers (pre-swizzled so linear LDS + swizzled read = identity)
  int krl0 = wid*8 + (lane >> 4), krl1 = krl0 + 4;          // K rows (8/wave, 2 issues)
  int kgs  = lane & 15;
  const u16* ks0 = Kh + (size_t)krl0 * HD + ((kgs ^ (krl0 & 7)) << 3);
  const u16* ks1 = Kh + (size_t)krl1 * HD + ((kgs ^ (krl1 & 7)) << 3);
  int vrl0 = wid*16 + (lane >> 3), vrl1 = vrl0 + 8;         // V d-rows (16/wave, 2 issues)
  int vgs  = lane & 7;
  const u16* vs0 = Vh + (size_t)vrl0 * SEQ + ((vgs ^ (vrl0 & 7)) << 3);
  const u16* vs1 = Vh + (size_t)vrl1 * SEQ + ((vgs ^ (vrl1 & 7)) << 3);

  // prologue: stage tile 0 into buffer 0
  gload16(ks0, &Ksm[0][wid*8][0]);
  gload16(ks1, &Ksm[0][wid*8 + 4][0]);
  gload16(vs0, &Vsm[0][wid*16][0]);
  gload16(vs1, &Vsm[0][wid*16 + 8][0]);
  __syncthreads();

  int ntr = 2*J + 2;
  int wrow0 = qb + wid*16;
  for (int t = 0; t < ntr; t++){
    int cur = t & 1, nxt = cur ^ 1;
    int kt0 = t << 6;
    if (t < ntr - 1){  // async prefetch tile t+1 (overlaps whole trip; drained at barrier)
      size_t ko = (size_t)(t + 1) * 64 * HD;
      gload16(ks0 + ko, &Ksm[nxt][wid*8][0]);
      gload16(ks1 + ko, &Ksm[nxt][wid*8 + 4][0]);
      int vo = (t + 1) * 64;
      gload16(vs0 + vo, &Vsm[nxt][wid*16][0]);
      gload16(vs1 + vo, &Vsm[nxt][wid*16 + 8][0]);
    }
    if (kt0 <= wrow0 + 15){   // wave has unmasked rows in this tile
      // QK^T from swizzled Ksm
      f32x4 s[4];
#pragma unroll
      for (int n = 0; n < 4; n++) s[n] = vz;
      const u16* kbase = &Ksm[cur][0][0];
#pragma unroll
      for (int n = 0; n < 4; n++){
        int row = n*16 + l16, rx = row & 7;
#pragma unroll
        for (int ks = 0; ks < 4; ks++){
          bf16x8 kf = *(const bf16x8*)(kbase + row*128 + (((ks*4 + lhi) ^ rx) << 3));
          s[n] = mfma16(qf[ks], kf, s[n]);
        }
      }
      // causal mask (diagonal region only)
      if (kt0 + 63 > wrow0){
#pragma unroll
        for (int n = 0; n < 4; n++)
#pragma unroll
          for (int i = 0; i < 4; i++)
            if (kt0 + n*16 + l16 > wrow0 + lhi*4 + i) s[n][i] = -1e30f;
      }
      // online softmax (row q lives in 16 lanes sharing lhi*4+i)
#pragma unroll
      for (int i = 0; i < 4; i++){
        float tm = fmaxf(fmaxf(s[0][i], s[1][i]), fmaxf(s[2][i], s[3][i]));
        tm = fmaxf(tm, __shfl_xor(tm, 1));
        tm = fmaxf(tm, __shfl_xor(tm, 2));
        tm = fmaxf(tm, __shfl_xor(tm, 4));
        tm = fmaxf(tm, __shfl_xor(tm, 8));
        float nm = fmaxf(mrow[i], tm);
        float sc = __expf(mrow[i] - nm);
        mrow[i] = nm;
        float rsum = 0.f;
#pragma unroll
        for (int n = 0; n < 4; n++){
          float p = __expf(s[n][i] - nm);
          s[n][i] = p;
          rsum += p;
        }
        rsum += __shfl_xor(rsum, 1);
        rsum += __shfl_xor(rsum, 2);
        rsum += __shfl_xor(rsum, 4);
        rsum += __shfl_xor(rsum, 8);
        lrow[i] = lrow[i] * sc + rsum;
#pragma unroll
        for (int n = 0; n < 8; n++) o[n][i] *= sc;
      }
      // P (D-layout) -> per-wave LDS (no barrier: same-wave producer/consumer)
#pragma unroll
      for (int n = 0; n < 4; n++)
#pragma unroll
        for (int i = 0; i < 4; i++)
          Psm[wid][lhi*4 + i][n*16 + l16] = f2bf(s[n][i]);
      // PV from swizzled Vsm
      const u16* vbase = &Vsm[cur][0][0];
#pragma unroll
      for (int ksv = 0; ksv < 2; ksv++){
        bf16x8 pa = *(const bf16x8*)&Psm[wid][l16][ksv*32 + lhi*8];
#pragma unroll
        for (int n = 0; n < 8; n++){
          int row = n*16 + l16;
          bf16x8 vb = *(const bf16x8*)(vbase + row*64 + ((((ksv*4) + lhi) ^ (row & 7)) << 3));
          o[n] = mfma16(pa, vb, o[n]);
        }
      }
    }
    if (t < ntr - 1) __syncthreads();  // drains prefetch (vmcnt0) + swaps buffers
  }
  // epilogue: O /= l, write bf16 to AO[t][hq*128 + d]
  float inv[4];
#pragma unroll
  for (int i = 0; i < 4; i++) inv[i] = 1.f / lrow[i];
#pragma unroll
  for (int n = 0; n < 8; n++)
#pragma unroll
    for (int i = 0; i < 4; i++){
      int trow = wrow0 + lhi*4 + i;
      AO[(size_t)trow * HID + hq * HD + n*16 + l16] = f2bf(o[n][i] * inv[i]);
    }
}

// ---------------- launch ----------------
extern "C" void kernel_launch(void* const* d_in, const int* in_sizes, int n_in,
                              void* d_out, int out_size, void* d_ws, size_t ws_size,
                              hipStream_t stream){
  const float* hs   = (const float*)d_in[0];
  const float* cosp = (const float*)d_in[1];
  const float* sinp = (const float*)d_in[2];
  const float* wqkv = (const float*)d_in[3];
  const float* wo   = (const float*)d_in[4];
  const float* qw   = (const float*)d_in[5];
  const float* kw   = (const float*)d_in[6];
  float* out = (float*)d_out;
  char* ws = (char*)d_ws;
  // workspace layout (128 MB total); WOT reuses XB/WQKVT region after GEMM1
  u16* XB    = (u16*)(ws + 0);            // 16.8 MB  X bf16 [2048][4096]
  u16* WQKVT = (u16*)(ws + 16777216);     // 50.3 MB  WqkvT bf16 [6144][4096]
  u16* WOT   = (u16*)(ws + 0);            // 33.6 MB  WoT bf16 [4096][4096] (after GEMM1)
  u16* QKV   = (u16*)(ws + 67108864);     // 25.2 MB  qkv bf16 [2048][6144]
  u16* QR    = (u16*)(ws + 92274688);     // 16.8 MB  Q bf16 [32][2048][128]
  u16* KR    = (u16*)(ws + 109051904);    //  4.2 MB  K bf16 [8][2048][128]
  u16* VTB   = (u16*)(ws + 113246208);    //  4.2 MB  VT bf16 [8][128][2048]
  u16* AOB   = (u16*)(ws + 117440512);    // 16.8 MB  attn out bf16 [2048][4096]

  k_cvt<<<(SEQ * HID / 4 + 255) / 256, 256, 0, stream>>>(hs, XB, SEQ * HID / 4);
  k_transpose_cvt<<<dim3(QKVN / 32, HID / 32), dim3(32, 8), 0, stream>>>(wqkv, WQKVT, HID, QKVN);
  k_gemm<1><<<dim3(QKVN / 128, SEQ / 128), 256, 0, stream>>>(XB, WQKVT, QKV, SEQ, QKVN, HID);
  k_transpose_cvt<<<dim3(HID / 32, HID / 32), dim3(32, 8), 0, stream>>>(wo, WOT, HID, HID);
  k_rmsrope<<<dim3(SEQ, 10), 256, 0, stream>>>(QKV, cosp, sinp, qw, kw, QR, KR);
  k_vt<<<dim3(SEQ / 32, HD / 32, NKVH), dim3(32, 8), 0, stream>>>(QKV, VTB);
  k_attn<<<512, 512, 0, stream>>>(QR, KR, VTB, AOB);
  k_gemm<0><<<dim3(HID / 128, SEQ / 128), 256, 0, stream>>>(AOB, WOT, out, SEQ, HID, HID);
}